// Round 7
// baseline (39.702 us; speedup 1.0000x reference)
//
#include <hip/hip_runtime.h>
#include <math.h>

#define N_PTS 4194304
#define M_CAM 2048
#define NG (N_PTS / 4)               // 1,048,576 groups of 4 points
#define THREADS 1024
#define BLOCKS 256
#define GSTRIDE (THREADS * BLOCKS)   // 262,144 threads; 4 groups per thread

// PROBE ROUND: kernel identical to R6; kernel_launch dispatches it TWICE
// (serialized in-stream) to separate fixed overhead OH from kernel time K:
//   R6:  dur = OH + K = 22.28 us
//   R7:  dur = OH + 2K   =>  K = dur7 - 22.28,  OH = 22.28 - K

__global__ __launch_bounds__(1024) void camera_project_fused(
        const float* __restrict__ X,
        const int* __restrict__ idx,
        const float* __restrict__ intr,
        const float* __restrict__ Rn,
        const float* __restrict__ tn,
        const float* __restrict__ intr_d,
        const float* __restrict__ rot_d,
        const float* __restrict__ trans_d,
        float* __restrict__ out) {
    __shared__ float4 l0[M_CAM];   // 32 KiB
    __shared__ float4 l1[M_CAM];   // 32 KiB
    __shared__ float4 l2[M_CAM];   // 32 KiB  -> 96 KiB total (1 block/CU)

    const int tid = blockIdx.x * THREADS + threadIdx.x;
    const float4* __restrict__ X4 = (const float4*)X;
    const int4* __restrict__ I4 = (const int4*)idx;
    float4* __restrict__ O4 = (float4*)out;

    // ---- Issue CAMERA loads first (build blocks on these; X loads queue behind) ----
    const int m0 = threadIdx.x;            // camera 0 of this thread
    const int m1 = threadIdx.x + THREADS;  // camera 1
    const float4* intr4 = (const float4*)intr;
    const float4* intrd4 = (const float4*)intr_d;

    float rd0x = rot_d[3 * m0 + 0], rd0y = rot_d[3 * m0 + 1], rd0z = rot_d[3 * m0 + 2];
    float rd1x = rot_d[3 * m1 + 0], rd1y = rot_d[3 * m1 + 1], rd1z = rot_d[3 * m1 + 2];
    float Rn0[9], Rn1[9];
#pragma unroll
    for (int j = 0; j < 9; ++j) Rn0[j] = Rn[9 * m0 + j];
#pragma unroll
    for (int j = 0; j < 9; ++j) Rn1[j] = Rn[9 * m1 + j];
    float tn0x = tn[3 * m0 + 0], tn0y = tn[3 * m0 + 1], tn0z = tn[3 * m0 + 2];
    float tn1x = tn[3 * m1 + 0], tn1y = tn[3 * m1 + 1], tn1z = tn[3 * m1 + 2];
    float td0x = trans_d[3 * m0 + 0], td0y = trans_d[3 * m0 + 1], td0z = trans_d[3 * m0 + 2];
    float td1x = trans_d[3 * m1 + 0], td1y = trans_d[3 * m1 + 1], td1z = trans_d[3 * m1 + 2];
    float4 ki0 = intr4[m0], kd0 = intrd4[m0];
    float4 ki1 = intr4[m1], kd1 = intrd4[m1];

    // ---- Prefetch groups 0 and 1 (stay in flight ACROSS the barrier) ----
    const int g0 = tid;
    const int g1 = g0 + GSTRIDE;
    float4 A0 = X4[3 * g0 + 0], B0 = X4[3 * g0 + 1], C0 = X4[3 * g0 + 2];
    int4 I0 = I4[g0];
    float4 A1 = X4[3 * g1 + 0], B1 = X4[3 * g1 + 1], C1 = X4[3 * g1 + 2];
    int4 I1 = I4[g1];

    // ---- Phase 1: build camera table (2 cameras per thread) ----
    auto build = [&](int m, float rx, float ry, float rz, const float* Rnl,
                     float tnx, float tny, float tnz,
                     float tdx, float tdy, float tdz, float4 ki, float4 kd) {
        float theta = sqrtf(rx * rx + ry * ry + rz * rz);
        float inv = 1.0f / fmaxf(theta, 1e-12f);
        float kx = rx * inv, ky = ry * inv, kz = rz * inv;
        float st = sinf(theta);
        float ct = cosf(theta);
        float omc = 1.0f - ct;

        float Rd[9];
        Rd[0] = 1.0f - omc * (ky * ky + kz * kz);
        Rd[1] = -st * kz + omc * (kx * ky);
        Rd[2] =  st * ky + omc * (kx * kz);
        Rd[3] =  st * kz + omc * (kx * ky);
        Rd[4] = 1.0f - omc * (kx * kx + kz * kz);
        Rd[5] = -st * kx + omc * (ky * kz);
        Rd[6] = -st * ky + omc * (kx * kz);
        Rd[7] =  st * kx + omc * (ky * kz);
        Rd[8] = 1.0f - omc * (kx * kx + ky * ky);

        float Rm[9];
#pragma unroll
        for (int i = 0; i < 3; ++i) {
#pragma unroll
            for (int j = 0; j < 3; ++j) {
                Rm[3 * i + j] = Rd[3 * i + 0] * Rnl[0 + j]
                              + Rd[3 * i + 1] * Rnl[3 + j]
                              + Rd[3 * i + 2] * Rnl[6 + j];
            }
        }

        float t0 = tnx + tdx, t1 = tny + tdy, t2 = tnz + tdz;
        float fx = ki.x + kd.x, fy = ki.y + kd.y;
        float cx = ki.z + kd.z, cy = ki.w + kd.w;

        l0[m] = make_float4(fmaf(fx, Rm[0], cx * Rm[6]),
                            fmaf(fx, Rm[1], cx * Rm[7]),
                            fmaf(fx, Rm[2], cx * Rm[8]),
                            fmaf(fx, t0, cx * t2));
        l1[m] = make_float4(fmaf(fy, Rm[3], cy * Rm[6]),
                            fmaf(fy, Rm[4], cy * Rm[7]),
                            fmaf(fy, Rm[5], cy * Rm[8]),
                            fmaf(fy, t1, cy * t2));
        l2[m] = make_float4(Rm[6], Rm[7], Rm[8], t2);
    };
    build(m0, rd0x, rd0y, rd0z, Rn0, tn0x, tn0y, tn0z, td0x, td0y, td0z, ki0, kd0);
    build(m1, rd1x, rd1y, rd1z, Rn1, tn1x, tn1y, tn1z, td1x, td1y, td1z, ki1, kd1);

    // Non-draining barrier: wait only for LDS writes; prefetches stay in flight.
    asm volatile("s_waitcnt lgkmcnt(0)" ::: "memory");
    __builtin_amdgcn_s_barrier();
    __builtin_amdgcn_sched_barrier(0);

    // ---- Phase 2: 2-deep prefetch pipeline over 4 groups ----
    auto proj = [&](int c, float px, float py, float pz) -> float2 {
        float4 r0 = l0[c];
        float4 r1 = l1[c];
        float4 r2 = l2[c];
        float nu = fmaf(r0.x, px, fmaf(r0.y, py, fmaf(r0.z, pz, r0.w)));
        float nv = fmaf(r1.x, px, fmaf(r1.y, py, fmaf(r1.z, pz, r1.w)));
        float zc = fmaf(r2.x, px, fmaf(r2.y, py, fmaf(r2.z, pz, r2.w)));
        float iz = 1.0f / zc;
        return make_float2(nu * iz, nv * iz);
    };
    auto process = [&](int g, float4 a, float4 b, float4 c, int4 ci) {
        float2 u0 = proj(ci.x, a.x, a.y, a.z);
        float2 u1 = proj(ci.y, a.w, b.x, b.y);
        float2 u2 = proj(ci.z, b.z, b.w, c.x);
        float2 u3 = proj(ci.w, c.y, c.z, c.w);
        O4[2 * g + 0] = make_float4(u0.x, u0.y, u1.x, u1.y);
        O4[2 * g + 1] = make_float4(u2.x, u2.y, u3.x, u3.y);
    };

    const int g2 = g0 + 2 * GSTRIDE;
    const int g3 = g0 + 3 * GSTRIDE;
    float4 A2 = X4[3 * g2 + 0], B2 = X4[3 * g2 + 1], C2 = X4[3 * g2 + 2];
    int4 I2 = I4[g2];
    float4 A3 = X4[3 * g3 + 0], B3 = X4[3 * g3 + 1], C3 = X4[3 * g3 + 2];
    int4 I3 = I4[g3];

    process(g0, A0, B0, C0, I0);
    process(g1, A1, B1, C1, I1);
    process(g2, A2, B2, C2, I2);
    process(g3, A3, B3, C3, I3);
}

extern "C" void kernel_launch(void* const* d_in, const int* in_sizes, int n_in,
                              void* d_out, int out_size, void* d_ws, size_t ws_size,
                              hipStream_t stream) {
    const float* X_world      = (const float*)d_in[0];
    const int*   cam_idx      = (const int*)d_in[1];
    const float* intrinsics   = (const float*)d_in[2];
    const float* R_noisy      = (const float*)d_in[3];
    const float* t_noisy      = (const float*)d_in[4];
    const float* intr_deltas  = (const float*)d_in[5];
    const float* rot_deltas   = (const float*)d_in[6];
    const float* trans_deltas = (const float*)d_in[7];
    float* out = (float*)d_out;

    // PROBE: dispatch twice (in-stream serialized; identical output).
    camera_project_fused<<<BLOCKS, THREADS, 0, stream>>>(
        X_world, cam_idx, intrinsics, R_noisy, t_noisy,
        intr_deltas, rot_deltas, trans_deltas, out);
    camera_project_fused<<<BLOCKS, THREADS, 0, stream>>>(
        X_world, cam_idx, intrinsics, R_noisy, t_noisy,
        intr_deltas, rot_deltas, trans_deltas, out);
}